// Round 8
// baseline (608.040 us; speedup 1.0000x reference)
//
#include <hip/hip_runtime.h>
#include <stdint.h>

// ---------------------------------------------------------------------------
// RelativeEncoderLayer. Round 12 (R11 + attn-only changes):
//  - attn: REVERT Pt physical-row permute (R3's permute moved the conflict
//    from cheap b16 stores to the hot b128 reads: 1.01e7 -> 1.43e7 measured;
//    unpermuted reads are bank-minimal at stride 36 dwords).
//  - attn LDS diet 48.6KB -> 36.25KB -> 4 blocks/CU:
//      * Racc stored DIRECTLY as bf16 [64][40] (it was only ever converted
//        to bf16 before its MFMA); conversion pass + 1 barrier deleted;
//        rows wave-private -> raf needs no barrier.
//      * qrel stored bf16 [64][34] (addend ~0.02, rounding ~1e-4 in exp).
//      * relvT aliased into Kt (dead after main loop); init in epilogue.
//  - gemm_bt (T2-swizzled 256x128) / tcast / cast4 / vtrans / ln_res: frozen.
// ---------------------------------------------------------------------------

typedef __bf16 bf16x8 __attribute__((ext_vector_type(8)));
typedef float  f32x4  __attribute__((ext_vector_type(4)));

__device__ __forceinline__ unsigned short f2bf(float f) {
  __bf16 h = (__bf16)f;                       // hardware RNE on gfx950
  union { __bf16 h; unsigned short u; } x; x.h = h;
  return x.u;
}
__device__ __forceinline__ float bf2f(unsigned short h) {
  union { unsigned u; float f; } x; x.u = ((unsigned)h) << 16; return x.f;
}

// Direct async global->LDS, 16B per lane. LDS dest is wave-uniform base +
// lane*16 (HW-fixed pattern); global src is per-lane.
__device__ __forceinline__ void gload_lds16(
    const unsigned short* g,
    __attribute__((address_space(3))) unsigned int* l) {
  __builtin_amdgcn_global_load_lds(
      (const __attribute__((address_space(1))) unsigned int*)g, l, 16, 0, 0);
}

// ---------------------------------------------------------------------------
// GEMM: C[M,N] = A[M,K] @ Bt[N,K]^T + bias.  256x128 tile, BK=64, 512 thr,
// 8 waves: wr=wv>>2 (row half, 128 rows), wc=wv&3 (col quarter, 32 cols).
// 3 LDS buffers x 48KB.  Stage-2-ahead counted-vmcnt pipeline (T4), 4
// phases x 8 MFMA with barrier+setprio (T3/T5).  XOR bank swizzle (T2):
// LDS[row][c] holds global col16 (c ^ (row&7)); reads XOR the same term.
// EPI: 0 = bias->bf16, 1 = bias->f32, 2 = bias+relu->bf16
// ---------------------------------------------------------------------------
template<int EPI>
__global__ __launch_bounds__(512, 2) void gemm_bt(
    const unsigned short* __restrict__ A,
    const unsigned short* __restrict__ Bt,
    const float* __restrict__ bias0,
    const float* __restrict__ bias1,
    const float* __restrict__ bias2,
    void* __restrict__ Cout,
    int M, int N, int K,
    size_t sA, size_t sB, size_t sC)
{
  // 3 buffers x (A 16384 + B 8192) ushorts = 73728 ushorts = 144KB
  __shared__ __align__(16) unsigned short S[3 * 24576];
  const int tid = threadIdx.x;
  const int lane = tid & 63, wv = tid >> 6;
  const int lq = lane >> 4, lm = lane & 15;
  const int wr = wv >> 2, wc = wv & 3;

  const int z = blockIdx.z;
  const float* bias = (z == 0) ? bias0 : (z == 1) ? bias1 : bias2;
  A  += (size_t)z * sA;
  Bt += (size_t)z * sB;

  // XCD-aware swizzle (hw id round-robins XCDs; nwg % 8 == 0 for all grids)
  const int nx = gridDim.x;
  const int nwg = nx * gridDim.y;
  int bid = blockIdx.y * nx + blockIdx.x;
  bid = (bid & 7) * (nwg >> 3) + (bid >> 3);
  const int m0 = (bid / nx) * 256, n0 = (bid % nx) * 128;

  // staging: thread covers row tid>>3 (+64 per chunk); global col16 is
  // PRE-SWIZZLED: col16' = (tid&7) ^ (row&7)  (row&7 invariant across +64g)
  const int srow = tid >> 3;
  const int scol = ((tid & 7) ^ (srow & 7)) * 8;       // elements
  const unsigned short* ga = A  + (size_t)(m0 + srow) * K + scol;
  const unsigned short* gb = Bt + (size_t)(n0 + srow) * K + scol;

  __attribute__((address_space(3))) unsigned int* lbase =
      (__attribute__((address_space(3))) unsigned int*)S;

  f32x4 acc[8][2] = {};

  auto stage = [&](int buf) {
    __attribute__((address_space(3))) unsigned int* lA = lbase + buf * 12288 + wv * 256;
    __attribute__((address_space(3))) unsigned int* lB = lA + 8192;
    #pragma unroll
    for (int g = 0; g < 4; ++g)
      gload_lds16(ga + (size_t)(g * 64) * K, lA + g * 2048);
    #pragma unroll
    for (int g = 0; g < 2; ++g)
      gload_lds16(gb + (size_t)(g * 64) * K, lB + g * 2048);
    ga += 64; gb += 64;
  };

  // fragment reads: row*128 + ((kk*4+lq)^(lm&7))*16 ; row&7 == lm&7 for
  // both A (wr*128+i*16+lm) and B (wc*32+j*16+lm) since 16|row-steps.
  const int csw0 = ((lq ^ (lm & 7)) << 4);             // kk=0 byte offset
  const int csw1 = csw0 ^ 64;                          // kk=1: (lq^4)^r7
  const char* fa = (const char*)S + (wr * 128 + lm) * 128;
  const char* fb = (const char*)S + 32768 + (wc * 32 + lm) * 128;

  auto compute_tile = [&](int buf) {
    const char* ba = fa + buf * 49152;
    const char* bb = fb + buf * 49152;
    bf16x8 bfr[2][2];
    #pragma unroll
    for (int j = 0; j < 2; ++j) {
      bfr[j][0] = *(const bf16x8*)(bb + j * 2048 + csw0);
      bfr[j][1] = *(const bf16x8*)(bb + j * 2048 + csw1);
    }
    #pragma unroll
    for (int q = 0; q < 4; ++q) {
      bf16x8 af[2][2];
      #pragma unroll
      for (int ii = 0; ii < 2; ++ii) {
        af[ii][0] = *(const bf16x8*)(ba + (q * 2 + ii) * 2048 + csw0);
        af[ii][1] = *(const bf16x8*)(ba + (q * 2 + ii) * 2048 + csw1);
      }
      __builtin_amdgcn_s_barrier();          // scheduling fence (intra-tile,
      __builtin_amdgcn_s_setprio(1);         //  read-only: no hazard)
      #pragma unroll
      for (int ii = 0; ii < 2; ++ii)
        #pragma unroll
        for (int j = 0; j < 2; ++j)
          #pragma unroll
          for (int kk = 0; kk < 2; ++kk)
            acc[q * 2 + ii][j] = __builtin_amdgcn_mfma_f32_16x16x32_bf16(
                af[ii][kk], bfr[j][kk], acc[q * 2 + ii][j], 0, 0, 0);
      __builtin_amdgcn_s_setprio(0);
      __builtin_amdgcn_s_barrier();
    }
  };

  const int nt = K >> 6;                 // 16 (K=1024) or 64 (K=4096)
  stage(0);
  stage(1);
  for (int t = 0; t < nt; ++t) {
    // own stage(t) complete; stage(t+1)'s 6 loads may remain in flight
    if (t + 1 < nt) asm volatile("s_waitcnt vmcnt(6)" ::: "memory");
    else            asm volatile("s_waitcnt vmcnt(0)" ::: "memory");
    __builtin_amdgcn_s_barrier();        // tile t visible everywhere; all
    __builtin_amdgcn_sched_barrier(0);   //  waves done reading buf[(t+2)%3]
    if (t + 2 < nt) stage((t + 2) % 3);
    compute_tile(t % 3);
  }

  #pragma unroll
  for (int i = 0; i < 8; ++i) {
    #pragma unroll
    for (int j = 0; j < 2; ++j) {
      const int col = n0 + wc * 32 + j * 16 + lm;
      const float bv = bias[col];
      #pragma unroll
      for (int r = 0; r < 4; ++r) {
        const int row = m0 + wr * 128 + i * 16 + lq * 4 + r;
        float v = acc[i][j][r] + bv;
        if (EPI == 2) v = fmaxf(v, 0.0f);
        if (EPI == 1) ((float*)Cout)[(size_t)row * N + col] = v;
        else ((unsigned short*)Cout + (size_t)z * sC)[(size_t)row * N + col] = f2bf(v);
      }
    }
  }
}

// ---------------------------------------------------------------------------
// Transpose-cast: out[C][R] bf16 = in[R][C] fp32.  32x32 LDS tiles.
// ---------------------------------------------------------------------------
__global__ __launch_bounds__(256) void tcast(
    const float* __restrict__ in, unsigned short* __restrict__ out, int R, int C)
{
  __shared__ float tile[32][33];
  const int tx = threadIdx.x & 31, ty = threadIdx.x >> 5;
  const int r0 = blockIdx.y * 32, c0 = blockIdx.x * 32;
  #pragma unroll
  for (int s = 0; s < 4; ++s)
    tile[ty + s * 8][tx] = in[(size_t)(r0 + ty + s * 8) * C + c0 + tx];
  __syncthreads();
  #pragma unroll
  for (int s = 0; s < 4; ++s)
    out[(size_t)(c0 + ty + s * 8) * R + r0 + tx] = f2bf(tile[tx][ty + s * 8]);
}

__global__ __launch_bounds__(256) void cast4(
    const float* __restrict__ in, unsigned short* __restrict__ out, int n)
{
  int i = (blockIdx.x * 256 + threadIdx.x) * 4;
  if (i < n) {
    float4 v = *(const float4*)(in + i);
    ushort4 o;
    o.x = f2bf(v.x); o.y = f2bf(v.y); o.z = f2bf(v.z); o.w = f2bf(v.w);
    *(ushort4*)(out + i) = o;
  }
}

// ---------------------------------------------------------------------------
// V-transpose: VP[8192 tok][1024] bf16 -> VPT[h][d][b][1024 pos] bf16.
// ---------------------------------------------------------------------------
__global__ __launch_bounds__(256) void vtrans(
    const unsigned short* __restrict__ VP, unsigned short* __restrict__ VPT)
{
  __shared__ unsigned short tile[64 * 66];
  const int pt = blockIdx.x, h = blockIdx.y, b = blockIdx.z;
  const int tid = threadIdx.x;
  const int p = tid >> 2, c0 = (tid & 3) * 16;
  const unsigned short* src = VP + (size_t)(b * 1024 + pt * 64 + p) * 1024 + h * 64 + c0;
  union { uint4 q; unsigned int u[4]; } t0, t1;
  t0.q = *(const uint4*)src;
  t1.q = *(const uint4*)(src + 8);
  #pragma unroll
  for (int e = 0; e < 4; ++e) {
    *(unsigned int*)&tile[p * 66 + c0 + e * 2]     = t0.u[e];
    *(unsigned int*)&tile[p * 66 + c0 + 8 + e * 2] = t1.u[e];
  }
  __syncthreads();
  const int d = tid >> 2, p0 = (tid & 3) * 16;
  union { uint4 q[2]; unsigned short s[16]; } ob;
  #pragma unroll
  for (int e = 0; e < 16; ++e) ob.s[e] = tile[(p0 + e) * 66 + d];
  unsigned short* dst = VPT + ((size_t)(h * 64 + d) * 8 + b) * 1024 + pt * 64 + p0;
  *(uint4*)dst       = ob.q[0];
  *(uint4*)(dst + 8) = ob.q[1];
}

// ---------------------------------------------------------------------------
// Flash attention with Shaw rel-pos (staged K/V, T14 register prefetch,
// XCD swizzle).  LDS 36.25KB -> 4 blocks/CU.  Pt logical rows (bank-minimal
// b128 reads at stride 36 dwords).  Racc/qrel stored bf16; relvT aliased
// into Kt (epilogue-only).
// ---------------------------------------------------------------------------
__global__ __launch_bounds__(256, 4) void attn_flash(
    const unsigned short* __restrict__ Qp,
    const unsigned short* __restrict__ Kp,
    const unsigned short* __restrict__ VPT,
    const float* __restrict__ relk,
    const float* __restrict__ relv,
    unsigned short* __restrict__ ctx)
{
  // XCD swizzle: each XCD owns one batch b (2048 = 8*256, bijective)
  int id = (blockIdx.z * gridDim.y + blockIdx.y) * gridDim.x + blockIdx.x;
  id = (id & 7) * 256 + (id >> 3);
  const int qt = id & 15, h = (id >> 4) & 15, b = id >> 8;

  const int tid = threadIdx.x;
  const int lane = tid & 63, wv = tid >> 6;
  const int lq = lane >> 4, lm = lane & 15;

  // Kt [64][72] | Vt [64][72] | Pt [64][72] | RaccB [64][40] | qrelB [64][34]
  // = 4608 + 4608 + 4608 + 2560 + 2176 ushorts = 37120 B
  __shared__ __align__(16) unsigned short SM[18560];
  unsigned short* Kt    = SM;              // [64][72]
  unsigned short* Vt    = SM + 4608;       // [64][72]
  unsigned short* Pt    = SM + 9216;       // [64][72]
  unsigned short* RaccB = SM + 13824;      // [64][40] bf16 (80B rows, aligned)
  unsigned short* qrelB = SM + 16384;      // [64][34] bf16
  unsigned short* relvT = SM;              // ALIAS of Kt, [64][32], epilogue

  const float CE = 0.125f * 1.44269504088896340736f;    // 1/sqrt(64) * log2(e)

  const int tok0 = b * 1024 + qt * 64;

  for (int i = tid; i < 64 * 40; i += 256) RaccB[i] = 0;

  // Q fragments (A-layout): rows wv*16+lm, d = {lq*8.., 32+lq*8..}
  bf16x8 qf0, qf1;
  {
    const unsigned short* qg = Qp + (size_t)(tok0 + wv * 16 + lm) * 1024 + h * 64;
    qf0 = *(const bf16x8*)(qg + lq * 8);
    qf1 = *(const bf16x8*)(qg + 32 + lq * 8);
  }

  // Srel = Q @ rel_k^T (bins 0..32, zero-padded tiles), pre-scaled by CE,
  // stored bf16 (addend ~0.02 -> rounding ~1e-4 in exp space, negligible)
  #pragma unroll
  for (int t = 0; t < 3; ++t) {
    const int bin = t * 16 + lm;
    union { bf16x8 v; unsigned short s[8]; } rk0, rk1;
    #pragma unroll
    for (int e = 0; e < 8; ++e) { rk0.s[e] = 0; rk1.s[e] = 0; }
    if (bin < 33) {
      const float* rp = relk + bin * 64 + lq * 8;
      #pragma unroll
      for (int e = 0; e < 8; ++e) {
        rk0.s[e] = f2bf(rp[e]);
        rk1.s[e] = f2bf(rp[32 + e]);
      }
    }
    f32x4 Sr = {};
    Sr = __builtin_amdgcn_mfma_f32_16x16x32_bf16(qf0, rk0.v, Sr, 0, 0, 0);
    Sr = __builtin_amdgcn_mfma_f32_16x16x32_bf16(qf1, rk1.v, Sr, 0, 0, 0);
    if (bin < 33) {
      #pragma unroll
      for (int r = 0; r < 4; ++r)
        qrelB[(wv * 16 + lq * 4 + r) * 34 + bin] = f2bf(Sr[r] * CE);
    }
  }
  __syncthreads();

  float q0a[4], q32a[4];
  #pragma unroll
  for (int r = 0; r < 4; ++r) {
    const int rowl = wv * 16 + lq * 4 + r;
    q0a[r]  = bf2f(qrelB[rowl * 34 + 0]);
    q32a[r] = bf2f(qrelB[rowl * 34 + 32]);
  }

  union { bf16x8 v; unsigned short s[8]; } one8;
  #pragma unroll
  for (int e = 0; e < 8; ++e) one8.s[e] = 0x3F80;       // bf16 1.0

  f32x4 Oa[4] = {};
  f32x4 Rs = {};                                        // row-sum accumulator
  float r0a[4] = {0, 0, 0, 0}, r32a[4] = {0, 0, 0, 0};

  const int srow = tid >> 2, scol = (tid & 3) * 16;
  const unsigned short* kg = Kp + (size_t)(b * 1024 + srow) * 1024 + h * 64 + scol;
  const unsigned short* vg = VPT + ((size_t)(h * 64 + srow) * 8 + b) * 1024 + scol;
  const int qa0 = qt * 64 + wv * 16;          // first absolute q-row of this wave

  // T14 prefetch: tile kt=0 into registers now
  uint4 rk0_ = *(const uint4*)(kg);
  uint4 rk1_ = *(const uint4*)(kg + 8);
  uint4 rv0_ = *(const uint4*)(vg);
  uint4 rv1_ = *(const uint4*)(vg + 8);

  for (int kt = 0; kt < 16; ++kt) {
    __syncthreads();                       // prev compute done reading Kt/Vt
    *(uint4*)(Kt + srow * 72 + scol)     = rk0_;
    *(uint4*)(Kt + srow * 72 + scol + 8) = rk1_;
    *(uint4*)(Vt + srow * 72 + scol)     = rv0_;
    *(uint4*)(Vt + srow * 72 + scol + 8) = rv1_;
    if (kt < 15) {
      kg += 64 * 1024;
      vg += 64;
      rk0_ = *(const uint4*)(kg);
      rk1_ = *(const uint4*)(kg + 8);
      rv0_ = *(const uint4*)(vg);
      rv1_ = *(const uint4*)(vg + 8);
    }
    __syncthreads();                       // staging visible

    #pragma unroll
    for (int tj = 0; tj < 4; ++tj) {
      bf16x8 kf0 = *(const bf16x8*)(Kt + (tj * 16 + lm) * 72 + lq * 8);
      bf16x8 kf1 = *(const bf16x8*)(Kt + (tj * 16 + lm) * 72 + 32 + lq * 8);
      f32x4 S = {};
      S = __builtin_amdgcn_mfma_f32_16x16x32_bf16(qf0, kf0, S, 0, 0, 0);
      S = __builtin_amdgcn_mfma_f32_16x16x32_bf16(qf1, kf1, S, 0, 0, 0);
      const int c0 = kt * 64 + tj * 16;
      if (c0 + 31 <= qa0) {
        #pragma unroll
        for (int r = 0; r < 4; ++r) {
          const float p = __builtin_amdgcn_exp2f(fmaf(S[r], CE, q0a[r]));
          r0a[r] += p;
          Pt[(wv * 16 + lq * 4 + r) * 72 + tj * 16 + lm] = f2bf(p);
        }
      } else if (c0 >= qa0 + 31) {
        #pragma unroll
        for (int r = 0; r < 4; ++r) {
          const float p = __builtin_amdgcn_exp2f(fmaf(S[r], CE, q32a[r]));
          r32a[r] += p;
          Pt[(wv * 16 + lq * 4 + r) * 72 + tj * 16 + lm] = f2bf(p);
        }
      } else {
        const int kpos = c0 + lm;
        #pragma unroll
        for (int r = 0; r < 4; ++r) {
          const int rowl = wv * 16 + lq * 4 + r;
          const int dist = kpos - (qt * 64 + rowl);
          const int bin = (dist < -16 ? 0 : (dist > 16 ? 32 : dist + 16));
          const float p =
              __builtin_amdgcn_exp2f(fmaf(S[r], CE, bf2f(qrelB[rowl * 34 + bin])));
          if (bin == 0)       r0a[r]  += p;
          else if (bin == 32) r32a[r] += p;
          else RaccB[rowl * 40 + bin] = f2bf(p);  // (row,bin 1..31) hit once
          Pt[rowl * 72 + tj * 16 + lm] = f2bf(p);
        }
      }
    }
    // Pt rows are wave-private: compiler lgkmcnt orders same-wave stores
    // before these b128 reads; no cross-wave hazard -> no barrier.
    bf16x8 pf0 = *(const bf16x8*)(Pt + (wv * 16 + lm) * 72 + lq * 8);
    bf16x8 pf1 = *(const bf16x8*)(Pt + (wv * 16 + lm) * 72 + 32 + lq * 8);
    Rs = __builtin_amdgcn_mfma_f32_16x16x32_bf16(pf0, one8.v, Rs, 0, 0, 0);
    Rs = __builtin_amdgcn_mfma_f32_16x16x32_bf16(pf1, one8.v, Rs, 0, 0, 0);
    #pragma unroll
    for (int dt = 0; dt < 4; ++dt) {
      bf16x8 vf0 = *(const bf16x8*)(Vt + (dt * 16 + lm) * 72 + lq * 8);
      bf16x8 vf1 = *(const bf16x8*)(Vt + (dt * 16 + lm) * 72 + 32 + lq * 8);
      Oa[dt] = __builtin_amdgcn_mfma_f32_16x16x32_bf16(pf0, vf0, Oa[dt], 0, 0, 0);
      Oa[dt] = __builtin_amdgcn_mfma_f32_16x16x32_bf16(pf1, vf1, Oa[dt], 0, 0, 0);
    }
  }

  // reduce per-lane clip-bin partials across the 16 lanes sharing each row
  #pragma unroll
  for (int r = 0; r < 4; ++r) {
    #pragma unroll
    for (int off = 1; off < 16; off <<= 1) {
      r0a[r]  += __shfl_xor(r0a[r],  off, 64);
      r32a[r] += __shfl_xor(r32a[r], off, 64);
    }
  }
  if (lm == 0) {
    #pragma unroll
    for (int r = 0; r < 4; ++r)
      RaccB[(wv * 16 + lq * 4 + r) * 40 + 0] = f2bf(r0a[r]);
  }
  __syncthreads();                      // all Kt reads done (main loop over)
  for (int i = tid; i < 64 * 32; i += 256) {
    const int dd = i >> 5, ss = i & 31;
    relvT[dd * 32 + ss] = f2bf(relv[ss * 64 + dd]);   // into Kt's storage
  }
  __syncthreads();                      // relvT visible to all waves

  // RaccB rows are wave-private (diagonal + col-0 writes by own wave):
  // in-wave lgkmcnt ordering suffices for raf.
  bf16x8 raf = *(const bf16x8*)(RaccB + (wv * 16 + lm) * 40 + lq * 8);
  #pragma unroll
  for (int dt = 0; dt < 4; ++dt) {
    bf16x8 rvb = *(const bf16x8*)(relvT + (dt * 16 + lm) * 32 + lq * 8);
    f32x4 O2 = {};
    O2 = __builtin_amdgcn_mfma_f32_16x16x32_bf16(raf, rvb, O2, 0, 0, 0);
    const float rv32 = relv[32 * 64 + dt * 16 + lm];
    #pragma unroll
    for (int r = 0; r < 4; ++r) {
      const int rowl = wv * 16 + lq * 4 + r;
      const float v = (Oa[dt][r] + O2[r] + r32a[r] * rv32) / Rs[r];
      ctx[(size_t)(tok0 + rowl) * 1024 + h * 64 + dt * 16 + lm] = f2bf(v);
    }
  }
}

// ---------------------------------------------------------------------------
// LayerNorm with residual: y = LN(x + res)*g + b -> fp32 (and optional bf16).
// ---------------------------------------------------------------------------
template<bool WB>
__global__ __launch_bounds__(256) void ln_res(
    const float* __restrict__ x, const float* __restrict__ res,
    const float* __restrict__ g, const float* __restrict__ bta,
    float* __restrict__ of, unsigned short* __restrict__ ob)
{
  const int row = blockIdx.x;
  const int tid = threadIdx.x;
  __shared__ float red[8];
  const size_t base = (size_t)row * 1024 + tid * 4;
  const float4 xv = *(const float4*)(x + base);
  const float4 rv = *(const float4*)(res + base);
  float v0 = xv.x + rv.x, v1 = xv.y + rv.y, v2 = xv.z + rv.z, v3 = xv.w + rv.w;
  float s1 = v0 + v1 + v2 + v3;
  float s2 = v0 * v0 + v1 * v1 + v2 * v2 + v3 * v3;
  #pragma unroll
  for (int off = 1; off < 64; off <<= 1) {
    s1 += __shfl_xor(s1, off, 64);
    s2 += __shfl_xor(s2, off, 64);
  }
  const int wv = tid >> 6;
  if ((tid & 63) == 0) { red[wv * 2] = s1; red[wv * 2 + 1] = s2; }
  __syncthreads();
  s1 = red[0] + red[2] + red[4] + red[6];
  s2 = red[1] + red[3] + red[5] + red[7];
  const float mean = s1 * (1.f / 1024.f);
  const float var = s2 * (1.f / 1024.f) - mean * mean;
  const float rstd = rsqrtf(var + 1e-6f);
  const float4 gv = *(const float4*)(g + tid * 4);
  const float4 bv = *(const float4*)(bta + tid * 4);
  float y0 = (v0 - mean) * rstd * gv.x + bv.x;
  float y1 = (v1 - mean) * rstd * gv.y + bv.y;
  float y2 = (v2 - mean) * rstd * gv.z + bv.z;
  float y3 = (v3 - mean) * rstd * gv.w + bv.w;
  float4 yo; yo.x = y0; yo.y = y1; yo.z = y2; yo.w = y3;
  *(float4*)(of + base) = yo;
  if (WB) {
    ushort4 o;
    o.x = f2bf(y0); o.y = f2bf(y1); o.z = f2bf(y2); o.w = f2bf(y3);
    *(ushort4*)(ob + base) = o;
  }
}

// ---------------------------------------------------------------------------
extern "C" void kernel_launch(void* const* d_in, const int* in_sizes, int n_in,
                              void* d_out, int out_size, void* d_ws, size_t ws_size,
                              hipStream_t stream) {
  (void)in_sizes; (void)n_in; (void)out_size; (void)ws_size;
  const float* q    = (const float*)d_in[0];
  const float* k    = (const float*)d_in[1];
  const float* v    = (const float*)d_in[2];
  const float* wq   = (const float*)d_in[3];
  const float* bq   = (const float*)d_in[4];
  const float* wk   = (const float*)d_in[5];
  const float* bk   = (const float*)d_in[6];
  const float* wv_  = (const float*)d_in[7];
  const float* bv   = (const float*)d_in[8];
  const float* wfc  = (const float*)d_in[9];
  const float* bfc  = (const float*)d_in[10];
  const float* w1   = (const float*)d_in[11];
  const float* b1   = (const float*)d_in[12];
  const float* w2   = (const float*)d_in[13];
  const float* b2   = (const float*)d_in[14];
  const float* ln_g = (const float*)d_in[15];
  const float* ln_b = (const float*)d_in[16];
  const float* rel_k = (const float*)d_in[17];
  const float* rel_v = (const float*)d_in[18];

  char* ws = (char*)d_ws;
  const size_t MB = 1ull << 20;
  unsigned short* WQT  = (unsigned short*)(ws + 0 * MB);
  unsigned short* WKT  = (unsigned short*)(ws + 2 * MB);
  unsigned short* WVT  = (unsigned short*)(ws + 4 * MB);
  unsigned short* WFCT = (unsigned short*)(ws + 6 * MB);
  unsigned short* W1T  = (unsigned short*)(ws + 8 * MB);    // [4096][1024]
  unsigned short* W2T  = (unsigned short*)(ws + 16 * MB);   // [1024][4096]
  unsigned short* QP   = (unsigned short*)(ws + 24 * MB);   // [24,40)
  unsigned short* KP   = (unsigned short*)(ws + 40 * MB);   // [40,56)
  unsigned short* VP   = (unsigned short*)(ws + 56 * MB);   // [56,72)
  unsigned short* QBF  = (unsigned short*)(ws + 72 * MB);   // [72,88)
  unsigned short* KBF  = (unsigned short*)(ws + 88 * MB);   // [88,104)
  unsigned short* VBF  = (unsigned short*)(ws + 104 * MB);  // [104,120)
  // lifetime reuse (all producers strictly after the region's last reader):
  unsigned short* VPT  = QBF;                               // [72,88)
  unsigned short* CTX  = KBF;                               // [88,104)
  float*          OTMP = (float*)(ws + 104 * MB);           // [104,136)
  float*          X1F  = (float*)(ws + 24 * MB);            // [24,56)
  unsigned short* X1BF = VP;                                // [56,72)
  unsigned short* HBUF = (unsigned short*)(ws + 72 * MB);   // [72,136)
  float*          Y2   = (float*)(ws + 136 * MB);           // [136,168)

  const dim3 blk(256);
  const dim3 gblk(512);
  const int NTOK = 8192;

  tcast<<<dim3(32, 32), blk, 0, stream>>>(wq, WQT, 1024, 1024);
  tcast<<<dim3(32, 32), blk, 0, stream>>>(wk, WKT, 1024, 1024);
  tcast<<<dim3(32, 32), blk, 0, stream>>>(wv_, WVT, 1024, 1024);
  tcast<<<dim3(32, 32), blk, 0, stream>>>(wfc, WFCT, 1024, 1024);
  tcast<<<dim3(128, 32), blk, 0, stream>>>(w1, W1T, 1024, 4096);
  tcast<<<dim3(32, 128), blk, 0, stream>>>(w2, W2T, 4096, 1024);
  cast4<<<8192, blk, 0, stream>>>(q, QBF, NTOK * 1024);
  cast4<<<8192, blk, 0, stream>>>(k, KBF, NTOK * 1024);
  cast4<<<8192, blk, 0, stream>>>(v, VBF, NTOK * 1024);

  // fused QKV: z picks A (QBF/KBF/VBF), B (WQT/WKT/WVT), bias, C (QP/KP/VP)
  gemm_bt<0><<<dim3(8, 32, 3), gblk, 0, stream>>>(
      QBF, WQT, bq, bk, bv, QP, NTOK, 1024, 1024,
      (size_t)8 * MB, (size_t)1 * MB, (size_t)8 * MB);

  vtrans<<<dim3(16, 16, 8), blk, 0, stream>>>(VP, VPT);

  attn_flash<<<dim3(16, 16, 8), blk, 0, stream>>>(QP, KP, VPT, rel_k, rel_v, CTX);

  gemm_bt<1><<<dim3(8, 32), gblk, 0, stream>>>(CTX, WFCT, bfc, bfc, bfc, OTMP,
                                               NTOK, 1024, 1024, 0, 0, 0);
  ln_res<true><<<8192, blk, 0, stream>>>(OTMP, q, ln_g, ln_b, X1F, X1BF);
  gemm_bt<2><<<dim3(32, 32), gblk, 0, stream>>>(X1BF, W1T, b1, b1, b1, HBUF,
                                                NTOK, 4096, 1024, 0, 0, 0);
  gemm_bt<1><<<dim3(8, 32), gblk, 0, stream>>>(HBUF, W2T, b2, b2, b2, Y2,
                                               NTOK, 1024, 4096, 0, 0, 0);
  ln_res<false><<<8192, blk, 0, stream>>>(Y2, X1F, ln_g, ln_b, (float*)d_out, nullptr);
}

// Round 9
// 572.036 us; speedup vs baseline: 1.0629x; 1.0629x over previous
//
#include <hip/hip_runtime.h>
#include <stdint.h>

// ---------------------------------------------------------------------------
// RelativeEncoderLayer. Round 13 (R12 + gemm-only changes):
//  - gemm_bt: 16-MFMA phases (was 8): B-frags hoisted per K-tile, quadrant =
//    MQ m-frags x all-n x 2kk.  Barriers per K-tile 9 -> 5.
//  - gemm_bt<_,256> (W1 only): 256x256 tile, 2 LDS buffers (128KB), 4
//    phases x 16 MFMA, counted vmcnt(8) at iter top (tile t landed; tile
//    t+1's 8 loads in flight -> no drain in loop).  Staging intensity
//    8 MFMA/KB vs 5.3 at 256x128.
//  - gemm_bt<_,128> (QKV/FC/W2): keeps proven 3-buf vmcnt(6) pipeline
//    (N=1024 grids need 256 blocks; BN=256 would idle half the CUs).
//  - attn_flash (R12 diet) / tcast / cast4 / vtrans / ln_res: frozen.
// ---------------------------------------------------------------------------

typedef __bf16 bf16x8 __attribute__((ext_vector_type(8)));
typedef float  f32x4  __attribute__((ext_vector_type(4)));

__device__ __forceinline__ unsigned short f2bf(float f) {
  __bf16 h = (__bf16)f;                       // hardware RNE on gfx950
  union { __bf16 h; unsigned short u; } x; x.h = h;
  return x.u;
}
__device__ __forceinline__ float bf2f(unsigned short h) {
  union { unsigned u; float f; } x; x.u = ((unsigned)h) << 16; return x.f;
}

// Direct async global->LDS, 16B per lane. LDS dest is wave-uniform base +
// lane*16 (HW-fixed pattern); global src is per-lane.
__device__ __forceinline__ void gload_lds16(
    const unsigned short* g,
    __attribute__((address_space(3))) unsigned int* l) {
  __builtin_amdgcn_global_load_lds(
      (const __attribute__((address_space(1))) unsigned int*)g, l, 16, 0, 0);
}

// ---------------------------------------------------------------------------
// GEMM: C[M,N] = A[M,K] @ Bt[N,K]^T + bias.  BM=256 x BN tile, BK=64,
// 512 thr / 8 waves (2 row-halves x 4 col-quarters; per-wave out
// 128 x BN/4).  T2 XOR bank swizzle (conflicts measured 0).  Pipelines:
//   BN=128: 3 buffers, stage-2-ahead, counted vmcnt(6)  [proven R11]
//   BN=256: 2 buffers, stage-1-ahead, counted vmcnt(8) at iter top
// Phases of 16 MFMA with barrier+setprio fencing (T3/T5).
// EPI: 0 = bias->bf16, 1 = bias->f32, 2 = bias+relu->bf16
// ---------------------------------------------------------------------------
template<int EPI, int BN>
__global__ __launch_bounds__(512, 2) void gemm_bt(
    const unsigned short* __restrict__ A,
    const unsigned short* __restrict__ Bt,
    const float* __restrict__ bias0,
    const float* __restrict__ bias1,
    const float* __restrict__ bias2,
    void* __restrict__ Cout,
    int M, int N, int K,
    size_t sA, size_t sB, size_t sC)
{
  constexpr int NJ   = BN / 64;              // n-frags per wave (2 or 4)
  constexpr int NB   = BN / 64;              // B chunks staged per tile
  constexpr int NP   = NJ;                   // phases (16 MFMA each)
  constexpr int MQ   = 8 / NP;               // m-frags per phase (4 or 2)
  constexpr int NBUF = (BN == 128) ? 3 : 2;
  constexpr int SBUF_US = 16384 + BN * 64;   // ushorts per buffer (A + B)
  constexpr int SBUF_DW = SBUF_US / 2;
  constexpr int SBUF_B  = SBUF_US * 2;

  __shared__ __align__(16) unsigned short S[NBUF * SBUF_US];
  const int tid = threadIdx.x;
  const int lane = tid & 63, wv = tid >> 6;
  const int lq = lane >> 4, lm = lane & 15;
  const int wr = wv >> 2, wc = wv & 3;

  const int z = blockIdx.z;
  const float* bias = (z == 0) ? bias0 : (z == 1) ? bias1 : bias2;
  A  += (size_t)z * sA;
  Bt += (size_t)z * sB;

  // XCD-aware swizzle (hw id round-robins XCDs; nwg % 8 == 0 for all grids)
  const int nx = gridDim.x;
  const int nwg = nx * gridDim.y;
  int bid = blockIdx.y * nx + blockIdx.x;
  bid = (bid & 7) * (nwg >> 3) + (bid >> 3);
  const int m0 = (bid / nx) * 256, n0 = (bid % nx) * BN;

  // staging: thread covers row tid>>3 (+64 per chunk); global col16 is
  // PRE-SWIZZLED: col16' = (tid&7) ^ (row&7)  (row&7 invariant across +64g)
  const int srow = tid >> 3;
  const int scol = ((tid & 7) ^ (srow & 7)) * 8;       // elements
  const unsigned short* ga = A  + (size_t)(m0 + srow) * K + scol;
  const unsigned short* gb = Bt + (size_t)(n0 + srow) * K + scol;

  __attribute__((address_space(3))) unsigned int* lbase =
      (__attribute__((address_space(3))) unsigned int*)S;

  f32x4 acc[8][NJ] = {};

  auto stage = [&](int buf) {
    __attribute__((address_space(3))) unsigned int* lA =
        lbase + buf * SBUF_DW + wv * 256;
    __attribute__((address_space(3))) unsigned int* lB = 
        lbase + buf * SBUF_DW + 8192 + wv * 256;
    #pragma unroll
    for (int g = 0; g < 4; ++g)
      gload_lds16(ga + (size_t)(g * 64) * K, lA + g * 2048);
    #pragma unroll
    for (int g = 0; g < NB; ++g)
      gload_lds16(gb + (size_t)(g * 64) * K, lB + g * 2048);
    ga += 64; gb += 64;
  };

  // fragment reads: row*128 + ((kk*4+lq)^(lm&7))*16 ; row&7 == lm&7 for
  // both A (wr*128+i*16+lm) and B (wc*(BN/4)+j*16+lm): all steps %8==0.
  const int csw0 = ((lq ^ (lm & 7)) << 4);             // kk=0 byte offset
  const int csw1 = csw0 ^ 64;                          // kk=1
  const char* fa = (const char*)S + (wr * 128 + lm) * 128;
  const char* fb = (const char*)S + 32768 + (wc * (BN / 4) + lm) * 128;

  auto compute_tile = [&](int buf) {
    const char* ba = fa + buf * SBUF_B;
    const char* bb = fb + buf * SBUF_B;
    bf16x8 bfr[NJ][2];
    #pragma unroll
    for (int j = 0; j < NJ; ++j) {
      bfr[j][0] = *(const bf16x8*)(bb + j * 2048 + csw0);
      bfr[j][1] = *(const bf16x8*)(bb + j * 2048 + csw1);
    }
    #pragma unroll
    for (int p = 0; p < NP; ++p) {
      bf16x8 af[MQ][2];
      #pragma unroll
      for (int ii = 0; ii < MQ; ++ii) {
        af[ii][0] = *(const bf16x8*)(ba + (p * MQ + ii) * 2048 + csw0);
        af[ii][1] = *(const bf16x8*)(ba + (p * MQ + ii) * 2048 + csw1);
      }
      __builtin_amdgcn_s_barrier();          // scheduling fence (intra-tile,
      __builtin_amdgcn_s_setprio(1);         //  read-only: no hazard)
      #pragma unroll
      for (int ii = 0; ii < MQ; ++ii)
        #pragma unroll
        for (int j = 0; j < NJ; ++j)
          #pragma unroll
          for (int kk = 0; kk < 2; ++kk)
            acc[p * MQ + ii][j] = __builtin_amdgcn_mfma_f32_16x16x32_bf16(
                af[ii][kk], bfr[j][kk], acc[p * MQ + ii][j], 0, 0, 0);
      __builtin_amdgcn_s_setprio(0);
      __builtin_amdgcn_s_barrier();
    }
  };

  const int nt = K >> 6;                 // 16 (K=1024) or 64 (K=4096)
  if constexpr (BN == 128) {
    // 3-buffer stage-2-ahead, counted vmcnt(6) (6 loads per stage)
    stage(0);
    stage(1);
    for (int t = 0; t < nt; ++t) {
      if (t + 1 < nt) asm volatile("s_waitcnt vmcnt(6)" ::: "memory");
      else            asm volatile("s_waitcnt vmcnt(0)" ::: "memory");
      __builtin_amdgcn_s_barrier();      // tile t visible everywhere; all
      __builtin_amdgcn_sched_barrier(0); //  waves done reading buf[(t+2)%3]
      if (t + 2 < nt) stage((t + 2) % 3);
      compute_tile(t % 3);
    }
  } else {
    // 2-buffer stage-1-ahead, counted vmcnt(8) (8 loads per stage).
    // compute_tile's trailing barrier = "all waves done reading cur",
    // so next iter's stage may overwrite it without extra sync.
    stage(0);
    for (int t = 0; t < nt; ++t) {
      if (t + 1 < nt) {
        stage((t + 1) & 1);              // 8 loads into the other buffer
        asm volatile("s_waitcnt vmcnt(8)" ::: "memory");  // tile t landed
      } else {
        asm volatile("s_waitcnt vmcnt(0)" ::: "memory");
      }
      __builtin_amdgcn_s_barrier();      // everyone's tile-t loads visible
      __builtin_amdgcn_sched_barrier(0);
      compute_tile(t & 1);
    }
  }

  #pragma unroll
  for (int i = 0; i < 8; ++i) {
    #pragma unroll
    for (int j = 0; j < NJ; ++j) {
      const int col = n0 + wc * (BN / 4) + j * 16 + lm;
      const float bv = bias[col];
      #pragma unroll
      for (int r = 0; r < 4; ++r) {
        const int row = m0 + wr * 128 + i * 16 + lq * 4 + r;
        float v = acc[i][j][r] + bv;
        if (EPI == 2) v = fmaxf(v, 0.0f);
        if (EPI == 1) ((float*)Cout)[(size_t)row * N + col] = v;
        else ((unsigned short*)Cout + (size_t)z * sC)[(size_t)row * N + col] = f2bf(v);
      }
    }
  }
}

// ---------------------------------------------------------------------------
// Transpose-cast: out[C][R] bf16 = in[R][C] fp32.  32x32 LDS tiles.
// ---------------------------------------------------------------------------
__global__ __launch_bounds__(256) void tcast(
    const float* __restrict__ in, unsigned short* __restrict__ out, int R, int C)
{
  __shared__ float tile[32][33];
  const int tx = threadIdx.x & 31, ty = threadIdx.x >> 5;
  const int r0 = blockIdx.y * 32, c0 = blockIdx.x * 32;
  #pragma unroll
  for (int s = 0; s < 4; ++s)
    tile[ty + s * 8][tx] = in[(size_t)(r0 + ty + s * 8) * C + c0 + tx];
  __syncthreads();
  #pragma unroll
  for (int s = 0; s < 4; ++s)
    out[(size_t)(c0 + ty + s * 8) * R + r0 + tx] = f2bf(tile[tx][ty + s * 8]);
}

__global__ __launch_bounds__(256) void cast4(
    const float* __restrict__ in, unsigned short* __restrict__ out, int n)
{
  int i = (blockIdx.x * 256 + threadIdx.x) * 4;
  if (i < n) {
    float4 v = *(const float4*)(in + i);
    ushort4 o;
    o.x = f2bf(v.x); o.y = f2bf(v.y); o.z = f2bf(v.z); o.w = f2bf(v.w);
    *(ushort4*)(out + i) = o;
  }
}

// ---------------------------------------------------------------------------
// V-transpose: VP[8192 tok][1024] bf16 -> VPT[h][d][b][1024 pos] bf16.
// ---------------------------------------------------------------------------
__global__ __launch_bounds__(256) void vtrans(
    const unsigned short* __restrict__ VP, unsigned short* __restrict__ VPT)
{
  __shared__ unsigned short tile[64 * 66];
  const int pt = blockIdx.x, h = blockIdx.y, b = blockIdx.z;
  const int tid = threadIdx.x;
  const int p = tid >> 2, c0 = (tid & 3) * 16;
  const unsigned short* src = VP + (size_t)(b * 1024 + pt * 64 + p) * 1024 + h * 64 + c0;
  union { uint4 q; unsigned int u[4]; } t0, t1;
  t0.q = *(const uint4*)src;
  t1.q = *(const uint4*)(src + 8);
  #pragma unroll
  for (int e = 0; e < 4; ++e) {
    *(unsigned int*)&tile[p * 66 + c0 + e * 2]     = t0.u[e];
    *(unsigned int*)&tile[p * 66 + c0 + 8 + e * 2] = t1.u[e];
  }
  __syncthreads();
  const int d = tid >> 2, p0 = (tid & 3) * 16;
  union { uint4 q[2]; unsigned short s[16]; } ob;
  #pragma unroll
  for (int e = 0; e < 16; ++e) ob.s[e] = tile[(p0 + e) * 66 + d];
  unsigned short* dst = VPT + ((size_t)(h * 64 + d) * 8 + b) * 1024 + pt * 64 + p0;
  *(uint4*)dst       = ob.q[0];
  *(uint4*)(dst + 8) = ob.q[1];
}

// ---------------------------------------------------------------------------
// Flash attention with Shaw rel-pos (staged K/V, T14 register prefetch,
// XCD swizzle).  LDS 36.25KB -> 4 blocks/CU.  Pt logical rows (bank-minimal
// b128 reads at stride 36 dwords).  Racc/qrel stored bf16; relvT aliased
// into Kt (epilogue-only).
// ---------------------------------------------------------------------------
__global__ __launch_bounds__(256, 4) void attn_flash(
    const unsigned short* __restrict__ Qp,
    const unsigned short* __restrict__ Kp,
    const unsigned short* __restrict__ VPT,
    const float* __restrict__ relk,
    const float* __restrict__ relv,
    unsigned short* __restrict__ ctx)
{
  // XCD swizzle: each XCD owns one batch b (2048 = 8*256, bijective)
  int id = (blockIdx.z * gridDim.y + blockIdx.y) * gridDim.x + blockIdx.x;
  id = (id & 7) * 256 + (id >> 3);
  const int qt = id & 15, h = (id >> 4) & 15, b = id >> 8;

  const int tid = threadIdx.x;
  const int lane = tid & 63, wv = tid >> 6;
  const int lq = lane >> 4, lm = lane & 15;

  // Kt [64][72] | Vt [64][72] | Pt [64][72] | RaccB [64][40] | qrelB [64][34]
  __shared__ __align__(16) unsigned short SM[18560];
  unsigned short* Kt    = SM;              // [64][72]
  unsigned short* Vt    = SM + 4608;       // [64][72]
  unsigned short* Pt    = SM + 9216;       // [64][72]
  unsigned short* RaccB = SM + 13824;      // [64][40] bf16 (80B rows, aligned)
  unsigned short* qrelB = SM + 16384;      // [64][34] bf16
  unsigned short* relvT = SM;              // ALIAS of Kt, [64][32], epilogue

  const float CE = 0.125f * 1.44269504088896340736f;    // 1/sqrt(64) * log2(e)

  const int tok0 = b * 1024 + qt * 64;

  for (int i = tid; i < 64 * 40; i += 256) RaccB[i] = 0;

  // Q fragments (A-layout): rows wv*16+lm, d = {lq*8.., 32+lq*8..}
  bf16x8 qf0, qf1;
  {
    const unsigned short* qg = Qp + (size_t)(tok0 + wv * 16 + lm) * 1024 + h * 64;
    qf0 = *(const bf16x8*)(qg + lq * 8);
    qf1 = *(const bf16x8*)(qg + 32 + lq * 8);
  }

  // Srel = Q @ rel_k^T (bins 0..32, zero-padded tiles), pre-scaled by CE,
  // stored bf16 (addend ~0.02 -> rounding ~1e-4 in exp space, negligible)
  #pragma unroll
  for (int t = 0; t < 3; ++t) {
    const int bin = t * 16 + lm;
    union { bf16x8 v; unsigned short s[8]; } rk0, rk1;
    #pragma unroll
    for (int e = 0; e < 8; ++e) { rk0.s[e] = 0; rk1.s[e] = 0; }
    if (bin < 33) {
      const float* rp = relk + bin * 64 + lq * 8;
      #pragma unroll
      for (int e = 0; e < 8; ++e) {
        rk0.s[e] = f2bf(rp[e]);
        rk1.s[e] = f2bf(rp[32 + e]);
      }
    }
    f32x4 Sr = {};
    Sr = __builtin_amdgcn_mfma_f32_16x16x32_bf16(qf0, rk0.v, Sr, 0, 0, 0);
    Sr = __builtin_amdgcn_mfma_f32_16x16x32_bf16(qf1, rk1.v, Sr, 0, 0, 0);
    if (bin < 33) {
      #pragma unroll
      for (int r = 0; r < 4; ++r)
        qrelB[(wv * 16 + lq * 4 + r) * 34 + bin] = f2bf(Sr[r] * CE);
    }
  }
  __syncthreads();

  float q0a[4], q32a[4];
  #pragma unroll
  for (int r = 0; r < 4; ++r) {
    const int rowl = wv * 16 + lq * 4 + r;
    q0a[r]  = bf2f(qrelB[rowl * 34 + 0]);
    q32a[r] = bf2f(qrelB[rowl * 34 + 32]);
  }

  union { bf16x8 v; unsigned short s[8]; } one8;
  #pragma unroll
  for (int e = 0; e < 8; ++e) one8.s[e] = 0x3F80;       // bf16 1.0

  f32x4 Oa[4] = {};
  f32x4 Rs = {};                                        // row-sum accumulator
  float r0a[4] = {0, 0, 0, 0}, r32a[4] = {0, 0, 0, 0};

  const int srow = tid >> 2, scol = (tid & 3) * 16;
  const unsigned short* kg = Kp + (size_t)(b * 1024 + srow) * 1024 + h * 64 + scol;
  const unsigned short* vg = VPT + ((size_t)(h * 64 + srow) * 8 + b) * 1024 + scol;
  const int qa0 = qt * 64 + wv * 16;          // first absolute q-row of this wave

  // T14 prefetch: tile kt=0 into registers now
  uint4 rk0_ = *(const uint4*)(kg);
  uint4 rk1_ = *(const uint4*)(kg + 8);
  uint4 rv0_ = *(const uint4*)(vg);
  uint4 rv1_ = *(const uint4*)(vg + 8);

  for (int kt = 0; kt < 16; ++kt) {
    __syncthreads();                       // prev compute done reading Kt/Vt
    *(uint4*)(Kt + srow * 72 + scol)     = rk0_;
    *(uint4*)(Kt + srow * 72 + scol + 8) = rk1_;
    *(uint4*)(Vt + srow * 72 + scol)     = rv0_;
    *(uint4*)(Vt + srow * 72 + scol + 8) = rv1_;
    if (kt < 15) {
      kg += 64 * 1024;
      vg += 64;
      rk0_ = *(const uint4*)(kg);
      rk1_ = *(const uint4*)(kg + 8);
      rv0_ = *(const uint4*)(vg);
      rv1_ = *(const uint4*)(vg + 8);
    }
    __syncthreads();                       // staging visible

    #pragma unroll
    for (int tj = 0; tj < 4; ++tj) {
      bf16x8 kf0 = *(const bf16x8*)(Kt + (tj * 16 + lm) * 72 + lq * 8);
      bf16x8 kf1 = *(const bf16x8*)(Kt + (tj * 16 + lm) * 72 + 32 + lq * 8);
      f32x4 S = {};
      S = __builtin_amdgcn_mfma_f32_16x16x32_bf16(qf0, kf0, S, 0, 0, 0);
      S = __builtin_amdgcn_mfma_f32_16x16x32_bf16(qf1, kf1, S, 0, 0, 0);
      const int c0 = kt * 64 + tj * 16;
      if (c0 + 31 <= qa0) {
        #pragma unroll
        for (int r = 0; r < 4; ++r) {
          const float p = __builtin_amdgcn_exp2f(fmaf(S[r], CE, q0a[r]));
          r0a[r] += p;
          Pt[(wv * 16 + lq * 4 + r) * 72 + tj * 16 + lm] = f2bf(p);
        }
      } else if (c0 >= qa0 + 31) {
        #pragma unroll
        for (int r = 0; r < 4; ++r) {
          const float p = __builtin_amdgcn_exp2f(fmaf(S[r], CE, q32a[r]));
          r32a[r] += p;
          Pt[(wv * 16 + lq * 4 + r) * 72 + tj * 16 + lm] = f2bf(p);
        }
      } else {
        const int kpos = c0 + lm;
        #pragma unroll
        for (int r = 0; r < 4; ++r) {
          const int rowl = wv * 16 + lq * 4 + r;
          const int dist = kpos - (qt * 64 + rowl);
          const int bin = (dist < -16 ? 0 : (dist > 16 ? 32 : dist + 16));
          const float p =
              __builtin_amdgcn_exp2f(fmaf(S[r], CE, bf2f(qrelB[rowl * 34 + bin])));
          if (bin == 0)       r0a[r]  += p;
          else if (bin == 32) r32a[r] += p;
          else RaccB[rowl * 40 + bin] = f2bf(p);  // (row,bin 1..31) hit once
          Pt[rowl * 72 + tj * 16 + lm] = f2bf(p);
        }
      }
    }
    // Pt rows are wave-private: compiler lgkmcnt orders same-wave stores
    // before these b128 reads; no cross-wave hazard -> no barrier.
    bf16x8 pf0 = *(const bf16x8*)(Pt + (wv * 16 + lm) * 72 + lq * 8);
    bf16x8 pf1 = *(const bf16x8*)(Pt + (wv * 16 + lm) * 72 + 32 + lq * 8);
    Rs = __builtin_amdgcn_mfma_f32_16x16x32_bf16(pf0, one8.v, Rs, 0, 0, 0);
    Rs = __builtin_amdgcn_mfma_f32_16x16x32_bf16(pf1, one8.v, Rs, 0, 0, 0);
    #pragma unroll
    for (int dt = 0; dt < 4; ++dt) {
      bf16x8 vf0 = *(const bf16x8*)(Vt + (dt * 16 + lm) * 72 + lq * 8);
      bf16x8 vf1 = *(const bf16x8*)(Vt + (dt * 16 + lm) * 72 + 32 + lq * 8);
      Oa[dt] = __builtin_amdgcn_mfma_f32_16x16x32_bf16(pf0, vf0, Oa[dt], 0, 0, 0);
      Oa[dt] = __builtin_amdgcn_mfma_f32_16x16x32_bf16(pf1, vf1, Oa[dt], 0, 0, 0);
    }
  }

  // reduce per-lane clip-bin partials across the 16 lanes sharing each row
  #pragma unroll
  for (int r = 0; r < 4; ++r) {
    #pragma unroll
    for (int off = 1; off < 16; off <<= 1) {
      r0a[r]  += __shfl_xor(r0a[r],  off, 64);
      r32a[r] += __shfl_xor(r32a[r], off, 64);
    }
  }
  if (lm == 0) {
    #pragma unroll
    for (int r = 0; r < 4; ++r)
      RaccB[(wv * 16 + lq * 4 + r) * 40 + 0] = f2bf(r0a[r]);
  }
  __syncthreads();                      // all Kt reads done (main loop over)
  for (int i = tid; i < 64 * 32; i += 256) {
    const int dd = i >> 5, ss = i & 31;
    relvT[dd * 32 + ss] = f2bf(relv[ss * 64 + dd]);   // into Kt's storage
  }
  __syncthreads();                      // relvT visible to all waves

  // RaccB rows are wave-private (diagonal + col-0 writes by own wave):
  // in-wave lgkmcnt ordering suffices for raf.
  bf16x8 raf = *(const bf16x8*)(RaccB + (wv * 16 + lm) * 40 + lq * 8);
  #pragma unroll
  for (int dt = 0; dt < 4; ++dt) {
    bf16x8 rvb = *(const bf16x8*)(relvT + (dt * 16 + lm) * 32 + lq * 8);
    f32x4 O2 = {};
    O2 = __builtin_amdgcn_mfma_f32_16x16x32_bf16(raf, rvb, O2, 0, 0, 0);
    const float rv32 = relv[32 * 64 + dt * 16 + lm];
    #pragma unroll
    for (int r = 0; r < 4; ++r) {
      const int rowl = wv * 16 + lq * 4 + r;
      const float v = (Oa[dt][r] + O2[r] + r32a[r] * rv32) / Rs[r];
      ctx[(size_t)(tok0 + rowl) * 1024 + h * 64 + dt * 16 + lm] = f2bf(v);
    }
  }
}

// ---------------------------------------------------------------------------
// LayerNorm with residual: y = LN(x + res)*g + b -> fp32 (and optional bf16).
// ---------------------------------------------------------------------------
template<bool WB>
__global__ __launch_bounds__(256) void ln_res(
    const float* __restrict__ x, const float* __restrict__ res,
    const float* __restrict__ g, const float* __restrict__ bta,
    float* __restrict__ of, unsigned short* __restrict__ ob)
{
  const int row = blockIdx.x;
  const int tid = threadIdx.x;
  __shared__ float red[8];
  const size_t base = (size_t)row * 1024 + tid * 4;
  const float4 xv = *(const float4*)(x + base);
  const float4 rv = *(const float4*)(res + base);
  float v0 = xv.x + rv.x, v1 = xv.y + rv.y, v2 = xv.z + rv.z, v3 = xv.w + rv.w;
  float s1 = v0 + v1 + v2 + v3;
  float s2 = v0 * v0 + v1 * v1 + v2 * v2 + v3 * v3;
  #pragma unroll
  for (int off = 1; off < 64; off <<= 1) {
    s1 += __shfl_xor(s1, off, 64);
    s2 += __shfl_xor(s2, off, 64);
  }
  const int wv = tid >> 6;
  if ((tid & 63) == 0) { red[wv * 2] = s1; red[wv * 2 + 1] = s2; }
  __syncthreads();
  s1 = red[0] + red[2] + red[4] + red[6];
  s2 = red[1] + red[3] + red[5] + red[7];
  const float mean = s1 * (1.f / 1024.f);
  const float var = s2 * (1.f / 1024.f) - mean * mean;
  const float rstd = rsqrtf(var + 1e-6f);
  const float4 gv = *(const float4*)(g + tid * 4);
  const float4 bv = *(const float4*)(bta + tid * 4);
  float y0 = (v0 - mean) * rstd * gv.x + bv.x;
  float y1 = (v1 - mean) * rstd * gv.y + bv.y;
  float y2 = (v2 - mean) * rstd * gv.z + bv.z;
  float y3 = (v3 - mean) * rstd * gv.w + bv.w;
  float4 yo; yo.x = y0; yo.y = y1; yo.z = y2; yo.w = y3;
  *(float4*)(of + base) = yo;
  if (WB) {
    ushort4 o;
    o.x = f2bf(y0); o.y = f2bf(y1); o.z = f2bf(y2); o.w = f2bf(y3);
    *(ushort4*)(ob + base) = o;
  }
}

// ---------------------------------------------------------------------------
extern "C" void kernel_launch(void* const* d_in, const int* in_sizes, int n_in,
                              void* d_out, int out_size, void* d_ws, size_t ws_size,
                              hipStream_t stream) {
  (void)in_sizes; (void)n_in; (void)out_size; (void)ws_size;
  const float* q    = (const float*)d_in[0];
  const float* k    = (const float*)d_in[1];
  const float* v    = (const float*)d_in[2];
  const float* wq   = (const float*)d_in[3];
  const float* bq   = (const float*)d_in[4];
  const float* wk   = (const float*)d_in[5];
  const float* bk   = (const float*)d_in[6];
  const float* wv_  = (const float*)d_in[7];
  const float* bv   = (const float*)d_in[8];
  const float* wfc  = (const float*)d_in[9];
  const float* bfc  = (const float*)d_in[10];
  const float* w1   = (const float*)d_in[11];
  const float* b1   = (const float*)d_in[12];
  const float* w2   = (const float*)d_in[13];
  const float* b2   = (const float*)d_in[14];
  const float* ln_g = (const float*)d_in[15];
  const float* ln_b = (const float*)d_in[16];
  const float* rel_k = (const float*)d_in[17];
  const float* rel_v = (const float*)d_in[18];

  char* ws = (char*)d_ws;
  const size_t MB = 1ull << 20;
  unsigned short* WQT  = (unsigned short*)(ws + 0 * MB);
  unsigned short* WKT  = (unsigned short*)(ws + 2 * MB);
  unsigned short* WVT  = (unsigned short*)(ws + 4 * MB);
  unsigned short* WFCT = (unsigned short*)(ws + 6 * MB);
  unsigned short* W1T  = (unsigned short*)(ws + 8 * MB);    // [4096][1024]
  unsigned short* W2T  = (unsigned short*)(ws + 16 * MB);   // [1024][4096]
  unsigned short* QP   = (unsigned short*)(ws + 24 * MB);   // [24,40)
  unsigned short* KP   = (unsigned short*)(ws + 40 * MB);   // [40,56)
  unsigned short* VP   = (unsigned short*)(ws + 56 * MB);   // [56,72)
  unsigned short* QBF  = (unsigned short*)(ws + 72 * MB);   // [72,88)
  unsigned short* KBF  = (unsigned short*)(ws + 88 * MB);   // [88,104)
  unsigned short* VBF  = (unsigned short*)(ws + 104 * MB);  // [104,120)
  // lifetime reuse (all producers strictly after the region's last reader):
  unsigned short* VPT  = QBF;                               // [72,88)
  unsigned short* CTX  = KBF;                               // [88,104)
  float*          OTMP = (float*)(ws + 104 * MB);           // [104,136)
  float*          X1F  = (float*)(ws + 24 * MB);            // [24,56)
  unsigned short* X1BF = VP;                                // [56,72)
  unsigned short* HBUF = (unsigned short*)(ws + 72 * MB);   // [72,136)
  float*          Y2   = (float*)(ws + 136 * MB);           // [136,168)

  const dim3 blk(256);
  const dim3 gblk(512);
  const int NTOK = 8192;

  tcast<<<dim3(32, 32), blk, 0, stream>>>(wq, WQT, 1024, 1024);
  tcast<<<dim3(32, 32), blk, 0, stream>>>(wk, WKT, 1024, 1024);
  tcast<<<dim3(32, 32), blk, 0, stream>>>(wv_, WVT, 1024, 1024);
  tcast<<<dim3(32, 32), blk, 0, stream>>>(wfc, WFCT, 1024, 1024);
  tcast<<<dim3(128, 32), blk, 0, stream>>>(w1, W1T, 1024, 4096);
  tcast<<<dim3(32, 128), blk, 0, stream>>>(w2, W2T, 4096, 1024);
  cast4<<<8192, blk, 0, stream>>>(q, QBF, NTOK * 1024);
  cast4<<<8192, blk, 0, stream>>>(k, KBF, NTOK * 1024);
  cast4<<<8192, blk, 0, stream>>>(v, VBF, NTOK * 1024);

  // fused QKV: z picks A (QBF/KBF/VBF), B (WQT/WKT/WVT), bias, C (QP/KP/VP)
  gemm_bt<0, 128><<<dim3(8, 32, 3), gblk, 0, stream>>>(
      QBF, WQT, bq, bk, bv, QP, NTOK, 1024, 1024,
      (size_t)8 * MB, (size_t)1 * MB, (size_t)8 * MB);

  vtrans<<<dim3(16, 16, 8), blk, 0, stream>>>(VP, VPT);

  attn_flash<<<dim3(16, 16, 8), blk, 0, stream>>>(QP, KP, VPT, rel_k, rel_v, CTX);

  gemm_bt<1, 128><<<dim3(8, 32), gblk, 0, stream>>>(CTX, WFCT, bfc, bfc, bfc, OTMP,
                                                    NTOK, 1024, 1024, 0, 0, 0);
  ln_res<true><<<8192, blk, 0, stream>>>(OTMP, q, ln_g, ln_b, X1F, X1BF);
  gemm_bt<2, 256><<<dim3(16, 32), gblk, 0, stream>>>(X1BF, W1T, b1, b1, b1, HBUF,
                                                     NTOK, 4096, 1024, 0, 0, 0);
  gemm_bt<1, 128><<<dim3(8, 32), gblk, 0, stream>>>(HBUF, W2T, b2, b2, b2, Y2,
                                                    NTOK, 1024, 4096, 0, 0, 0);
  ln_res<false><<<8192, blk, 0, stream>>>(Y2, X1F, ln_g, ln_b, (float*)d_out, nullptr);
}